// Round 4
// baseline (214.063 us; speedup 1.0000x reference)
//
#include <hip/hip_runtime.h>
#include <hip/hip_bf16.h>

typedef __hip_bfloat16 bf16;
typedef __attribute__((ext_vector_type(8))) short short8;   // 8 bf16 = 4 VGPRs (x32 A/B frag)
typedef __attribute__((ext_vector_type(4))) short short4v;  // 4 bf16 = 2 VGPRs (x16 A/B frag)
typedef __attribute__((ext_vector_type(4))) float f32x4;    // MFMA C/D frag

#define MFMA16(a, b, c) __builtin_amdgcn_mfma_f32_16x16x32_bf16((a), (b), (c), 0, 0, 0)

// 16x16x16 bf16 MFMA: builtin name varies across ROCm; asm fallback.
#if __has_builtin(__builtin_amdgcn_mfma_f32_16x16x16bf16_1k)
#define MFMA_PV(a, b, c) __builtin_amdgcn_mfma_f32_16x16x16bf16_1k((a), (b), (c), 0, 0, 0)
#elif __has_builtin(__builtin_amdgcn_mfma_f32_16x16x16_bf16)
#define MFMA_PV(a, b, c) __builtin_amdgcn_mfma_f32_16x16x16_bf16((a), (b), (c), 0, 0, 0)
#else
static __device__ __forceinline__ f32x4 mfma_pv_asm(short4v a, short4v b, f32x4 c) {
    f32x4 d;
    asm volatile("v_mfma_f32_16x16x16_bf16 %0, %1, %2, %3"
                 : "=&v"(d) : "v"(a), "v"(b), "v"(c));
    return d;
}
#define MFMA_PV(a, b, c) mfma_pv_asm((a), (b), (c))
#endif

// async global->LDS, 16B per lane; LDS dest must be wave-uniform base + lane*16
static __device__ __forceinline__ void gload_lds16(const bf16* g, bf16* l) {
    __builtin_amdgcn_global_load_lds((const __attribute__((address_space(1))) void*)g,
                                     (__attribute__((address_space(3))) void*)l, 16, 0, 0);
}

// ---------------------------------------------------------------------------
// Kernel 1: cast x (fp32) -> bf16
// ---------------------------------------------------------------------------
__global__ __launch_bounds__(256) void cast_x_kernel(const float* __restrict__ in,
                                                     bf16* __restrict__ out) {
    int i = (blockIdx.x * 256 + threadIdx.x) * 4;
    float4 v = *(const float4*)(in + i);
    union { bf16 h4[4]; uint2 u; } p;
    p.h4[0] = __float2bfloat16(v.x);
    p.h4[1] = __float2bfloat16(v.y);
    p.h4[2] = __float2bfloat16(v.z);
    p.h4[3] = __float2bfloat16(v.w);
    *(uint2*)(out + i) = p.u;
}

// ---------------------------------------------------------------------------
// Kernel 2: transpose + cast weights (64x64 LDS tiles)
// ---------------------------------------------------------------------------
__global__ __launch_bounds__(256) void transpose_cast_kernel(
    const float* __restrict__ wq, const float* __restrict__ wk,
    const float* __restrict__ wv, const float* __restrict__ wo,
    bf16* __restrict__ WqkvT, bf16* __restrict__ WoT) {
    __shared__ bf16 tile[64][65];
    int bid = blockIdx.x;
    int mat = bid >> 8;
    int t   = bid & 255;
    int tn  = t >> 4, tk = t & 15;
    const float* src = (mat == 0) ? wq : (mat == 1) ? wk : (mat == 2) ? wv : wo;
    bf16* dst = (mat < 3) ? (WqkvT + (size_t)mat * 1024 * 1024) : WoT;
    int tx = threadIdx.x & 63, ty = threadIdx.x >> 6;
    int k0 = tk * 64, n0 = tn * 64;
#pragma unroll
    for (int p = 0; p < 16; ++p) {
        int r = p * 4 + ty;
        tile[r][tx] = __float2bfloat16(src[(size_t)(k0 + r) * 1024 + n0 + tx]);
    }
    __syncthreads();
#pragma unroll
    for (int p = 0; p < 16; ++p) {
        int r = p * 4 + ty;
        dst[(size_t)(n0 + r) * 1024 + k0 + tx] = tile[tx][r];
    }
}

// ---------------------------------------------------------------------------
// Kernel 3: GEMM1  QKV = Xb @ WqkvT^T, global_load_lds staging.
// Q columns (bn<8) are PRESCALED by 0.125*log2(e) for the attn softmax.
// ---------------------------------------------------------------------------
__global__ __launch_bounds__(256) void gemm_qkv_kernel(
    const bf16* __restrict__ A, const bf16* __restrict__ Bt,
    bf16* __restrict__ QK, bf16* __restrict__ Vt) {
    const int K = 1024;
    int bm = blockIdx.x, bn = blockIdx.y;
    __shared__ bf16 As[128 * 32];
    __shared__ bf16 Bs[128 * 32];
    int tid = threadIdx.x;
    int lane = tid & 63, w = tid >> 6;
    int wm = (w >> 1) * 64, wn = (w & 1) * 64;
    int q4 = lane >> 4, li = lane & 15;
    int srow = tid >> 2, sc = (tid & 3) * 8;

    const bf16* Ag = A + (size_t)(bm * 128 + srow) * K + sc;
    const bf16* Bg = Bt + (size_t)(bn * 128 + srow) * K + sc;
    bf16* Asl = As + tid * 8;
    bf16* Asl2 = As + 2048 + tid * 8;
    bf16* Bsl = Bs + tid * 8;
    bf16* Bsl2 = Bs + 2048 + tid * 8;

    f32x4 acc[4][4];
#pragma unroll
    for (int mt = 0; mt < 4; ++mt)
#pragma unroll
        for (int nt = 0; nt < 4; ++nt) acc[mt][nt] = (f32x4){0.f, 0.f, 0.f, 0.f};

    for (int k0 = 0; k0 < K; k0 += 32) {
        __syncthreads();
        gload_lds16(Ag + k0, Asl);
        gload_lds16(Ag + 64 * K + k0, Asl2);
        gload_lds16(Bg + k0, Bsl);
        gload_lds16(Bg + 64 * K + k0, Bsl2);
        __syncthreads();
        short8 af[4], bfb[4];
#pragma unroll
        for (int mt = 0; mt < 4; ++mt)
            af[mt] = *(const short8*)(As + (wm + mt * 16 + li) * 32 + q4 * 8);
#pragma unroll
        for (int nt = 0; nt < 4; ++nt)
            bfb[nt] = *(const short8*)(Bs + (wn + nt * 16 + li) * 32 + q4 * 8);
#pragma unroll
        for (int mt = 0; mt < 4; ++mt)
#pragma unroll
            for (int nt = 0; nt < 4; ++nt)
                acc[mt][nt] = MFMA16(af[mt], bfb[nt], acc[mt][nt]);
    }

    int rowb = bm * 128 + wm;
    if (bn < 16) {
        float qs = (bn < 8) ? 0.1803368801111244f : 1.0f;   // 0.125*log2(e) on Q
#pragma unroll
        for (int mt = 0; mt < 4; ++mt) {
#pragma unroll
            for (int nt = 0; nt < 4; ++nt) {
                int col = bn * 128 + wn + nt * 16 + li;
#pragma unroll
                for (int r = 0; r < 4; ++r) {
                    int row = rowb + mt * 16 + q4 * 4 + r;
                    QK[(size_t)row * 2048 + col] = __float2bfloat16(acc[mt][nt][r] * qs);
                }
            }
        }
    } else {
#pragma unroll
        for (int mt = 0; mt < 4; ++mt) {
            int sbase = rowb + mt * 16 + q4 * 4;
            int b = sbase >> 11, s = sbase & 2047;
#pragma unroll
            for (int nt = 0; nt < 4; ++nt) {
                int n = bn * 128 + wn + nt * 16 + li - 2048;
                int h = n >> 6, d = n & 63;
                union { bf16 h4[4]; uint2 u; } pk;
#pragma unroll
                for (int r = 0; r < 4; ++r) pk.h4[r] = __float2bfloat16(acc[mt][nt][r]);
                *(uint2*)(Vt + (size_t)((b * 16 + h) * 64 + d) * 2048 + s) = pk.u;
            }
        }
    }
}

// ---------------------------------------------------------------------------
// Kernel 4: flash attention, q-split S^T + double-buffered LDS prefetch.
//  - wave w owns q rows iw..iw+15; S^T = K·Q^T (A=K, B=Q).
//  - S^T C-regs (j=q4*4+r, i=li) ARE the B-frag of PV as O^T = V^T·P:
//    no P LDS round trip, no cross-wave O reduce.
//  - 1 barrier/tile: write tile jt+1 into buf[(jt+1)&1] while computing
//    buf[jt&1]; global loads for jt+2 in flight across the compute phase.
//  - Q prescaled by 0.125*log2e in gemm_qkv; softmax in exp2 domain.
// ---------------------------------------------------------------------------
__global__ __launch_bounds__(256, 4) void attn_kernel(
    const bf16* __restrict__ QK, const bf16* __restrict__ Vt,
    const float* __restrict__ x, const float* __restrict__ gch,
    bf16* __restrict__ AO) {
    const int S = 2048;
    // LPT schedule: h=0 blocks (32 tiles) first, then causal descending ti.
    int idx = blockIdx.x;
    int ti, h, b;
    if (idx < 64) { h = 0; b = idx & 1; ti = idx >> 1; }
    else {
        int i2 = idx - 64;
        int row = i2 / 30;
        int j = i2 - row * 30;
        ti = 31 - row; h = 1 + (j >> 1); b = j & 1;
    }
    int i0 = ti * 64;
    int tid = threadIdx.x, lane = tid & 63, w = tid >> 6;
    int q4 = lane >> 4, li = lane & 15;

    __shared__ bf16 Ks[2][64 * 72];   // K tile [j][d], +8 pad, double-buffered
    __shared__ bf16 Vs[2][64 * 72];   // V^T tile [d][j], +8 pad

    int iG = i0 + w * 16 + li;        // this lane's query row (fixed)

    // Q frag (B-operand of S^T): B[n=li][k=q4*8+..]
    const bf16* qp = QK + (size_t)(b * S + iG) * 2048 + h * 64 + q4 * 8;
    short8 qf0 = *(const short8*)(qp);
    short8 qf1 = *(const short8*)(qp + 32);

    const float L2E = 1.4426950408889634f;
    float sl1 = exp2f(-0.5f * (float)(h + 1)) * L2E;   // coeff of (j - i)
    const float slope0L = 0.70710678118654752f * L2E;

    float tgj = 0.f; bool gcm = false;
    if (h == 0) {
        size_t ix = (size_t)(b * S + iG);
        gcm = gch[ix] > 0.5f;
        tgj = x[ix * 1024 + 1008] + 1.0f + x[ix * 1024 + 1009] - (float)iG;
    }

    float lsum = 0.f;
    f32x4 o[4];                        // O^T accum: (d=dt*16+q4*4+r, i=li)
#pragma unroll
    for (int dt = 0; dt < 4; ++dt) o[dt] = (f32x4){0.f, 0.f, 0.f, 0.f};

    int srow = tid >> 3, scv = (tid & 7) * 8;
    const bf16* Kg = QK + (size_t)(b * S + srow) * 2048 + 1024 + h * 64 + scv;
    const bf16* Vg = Vt + (size_t)((b * 16 + h) * 64 + srow) * 2048 + scv;

    int ntiles = (h == 0) ? (S / 64) : (ti + 1);

    // prologue: stage tile 0, prefetch tile 1
    uint4 kv0 = *(const uint4*)(Kg);
    uint4 kv1 = *(const uint4*)(Kg + (size_t)32 * 2048);
    uint4 vv0 = *(const uint4*)(Vg);
    uint4 vv1 = *(const uint4*)(Vg + (size_t)32 * 2048);
    *(uint4*)(Ks[0] + srow * 72 + scv) = kv0;
    *(uint4*)(Ks[0] + (srow + 32) * 72 + scv) = kv1;
    *(uint4*)(Vs[0] + srow * 72 + scv) = vv0;
    *(uint4*)(Vs[0] + (srow + 32) * 72 + scv) = vv1;
    if (ntiles > 1) {
        kv0 = *(const uint4*)(Kg + (size_t)64 * 2048);
        kv1 = *(const uint4*)(Kg + (size_t)96 * 2048);
        vv0 = *(const uint4*)(Vg + 64);
        vv1 = *(const uint4*)(Vg + (size_t)32 * 2048 + 64);
    }
    __syncthreads();

    for (int jt = 0; jt < ntiles; ++jt) {
        const bf16* KsB = Ks[jt & 1];
        const bf16* VsB = Vs[jt & 1];
        if (jt + 1 < ntiles) {
            bf16* Kn = Ks[(jt + 1) & 1];
            bf16* Vn = Vs[(jt + 1) & 1];
            *(uint4*)(Kn + srow * 72 + scv) = kv0;
            *(uint4*)(Kn + (srow + 32) * 72 + scv) = kv1;
            *(uint4*)(Vn + srow * 72 + scv) = vv0;
            *(uint4*)(Vn + (srow + 32) * 72 + scv) = vv1;
            if (jt + 2 < ntiles) {
                size_t jn = (size_t)(jt + 2) * 64;
                kv0 = *(const uint4*)(Kg + jn * 2048);
                kv1 = *(const uint4*)(Kg + (jn + 32) * 2048);
                vv0 = *(const uint4*)(Vg + jn);
                vv1 = *(const uint4*)(Vg + (size_t)32 * 2048 + jn);
            }
        }

        int j0 = jt * 64;
        // S^T: per j-subtile nt, rows j=nt*16+q4*4+r, cols i=li
        f32x4 sA[4];
#pragma unroll
        for (int nt = 0; nt < 4; ++nt) {
            short8 kf0 = *(const short8*)(KsB + (nt * 16 + li) * 72 + q4 * 8);
            short8 kf1 = *(const short8*)(KsB + (nt * 16 + li) * 72 + 32 + q4 * 8);
            f32x4 z = (f32x4){0.f, 0.f, 0.f, 0.f};
            z = MFMA16(kf0, qf0, z);
            z = MFMA16(kf1, qf1, z);
            sA[nt] = z;
        }

        bool diag = (jt >= ti);
        short4v pB[4];
#pragma unroll
        for (int nt = 0; nt < 4; ++nt) {
            float djb = (float)(j0 + nt * 16 + q4 * 4 - iG);
            union { bf16 hh[4]; short4v v; } pu;
#pragma unroll
            for (int r = 0; r < 4; ++r) {
                float dj = djb + (float)r;
                float p;
                if (h == 0) {
                    float s = fmaf(sl1, dj, sA[nt][r]);
                    float sg = -slope0L * fabsf(tgj - dj);
                    s = gcm ? sg : s;
                    p = exp2f(s);
                    if (!gcm && dj > 0.f) p = 0.f;
                } else {
                    float s = fmaf(sl1, dj, sA[nt][r]);
                    p = exp2f(s);
                    if (diag && dj > 0.f) p = 0.f;
                }
                lsum += p;
                pu.hh[r] = __float2bfloat16(p);
            }
            pB[nt] = pu.v;
        }

        // PV: O^T += V^T · P  (A = V^T frag from LDS, B = pB in regs)
#pragma unroll
        for (int nt = 0; nt < 4; ++nt) {
#pragma unroll
            for (int dt = 0; dt < 4; ++dt) {
                short4v vf = *(const short4v*)(VsB + (dt * 16 + li) * 72 + nt * 16 + q4 * 4);
                o[dt] = MFMA_PV(vf, pB[nt], o[dt]);
            }
        }
        __syncthreads();
    }

    // lsum: combine the 4 q4 groups sharing the same i (=li)
    lsum += __shfl_xor(lsum, 16, 64);
    lsum += __shfl_xor(lsum, 32, 64);
    float inv = 1.0f / lsum;

    bf16* dst = AO + (size_t)(b * S + iG) * 1024 + h * 64 + q4 * 4;
#pragma unroll
    for (int dt = 0; dt < 4; ++dt) {
        union { bf16 h4[4]; uint2 u; } ou;
#pragma unroll
        for (int r = 0; r < 4; ++r) ou.h4[r] = __float2bfloat16(o[dt][r] * inv);
        *(uint2*)(dst + dt * 16) = ou.u;
    }
}

// ---------------------------------------------------------------------------
// Kernel 5: GEMM2  out = x + AO @ WoT^T (fp32 out) + fused I/O fixups
// ---------------------------------------------------------------------------
__global__ __launch_bounds__(256) void gemm_out_kernel(
    const bf16* __restrict__ A, const bf16* __restrict__ Bt,
    const float* __restrict__ x, const float* __restrict__ gch,
    const float* __restrict__ pch, float* __restrict__ out) {
    const int K = 1024;
    int bm = blockIdx.x, bn = blockIdx.y;
    __shared__ bf16 As[128 * 32];
    __shared__ bf16 Bs[128 * 32];
    int tid = threadIdx.x;
    int lane = tid & 63, w = tid >> 6;
    int wm = (w >> 1) * 64, wn = (w & 1) * 64;
    int q4 = lane >> 4, li = lane & 15;
    int srow = tid >> 2, sc = (tid & 3) * 8;

    const bf16* Ag = A + (size_t)(bm * 128 + srow) * K + sc;
    const bf16* Bg = Bt + (size_t)(bn * 128 + srow) * K + sc;
    bf16* Asl = As + tid * 8;
    bf16* Asl2 = As + 2048 + tid * 8;
    bf16* Bsl = Bs + tid * 8;
    bf16* Bsl2 = Bs + 2048 + tid * 8;

    f32x4 acc[4][4];
#pragma unroll
    for (int mt = 0; mt < 4; ++mt)
#pragma unroll
        for (int nt = 0; nt < 4; ++nt) acc[mt][nt] = (f32x4){0.f, 0.f, 0.f, 0.f};

    for (int k0 = 0; k0 < K; k0 += 32) {
        __syncthreads();
        gload_lds16(Ag + k0, Asl);
        gload_lds16(Ag + 64 * K + k0, Asl2);
        gload_lds16(Bg + k0, Bsl);
        gload_lds16(Bg + 64 * K + k0, Bsl2);
        __syncthreads();
        short8 af[4], bfb[4];
#pragma unroll
        for (int mt = 0; mt < 4; ++mt)
            af[mt] = *(const short8*)(As + (wm + mt * 16 + li) * 32 + q4 * 8);
#pragma unroll
        for (int nt = 0; nt < 4; ++nt)
            bfb[nt] = *(const short8*)(Bs + (wn + nt * 16 + li) * 32 + q4 * 8);
#pragma unroll
        for (int mt = 0; mt < 4; ++mt)
#pragma unroll
            for (int nt = 0; nt < 4; ++nt)
                acc[mt][nt] = MFMA16(af[mt], bfb[nt], acc[mt][nt]);
    }

#pragma unroll
    for (int mt = 0; mt < 4; ++mt) {
#pragma unroll
        for (int nt = 0; nt < 4; ++nt) {
            int col = bn * 128 + wn + nt * 16 + li;
#pragma unroll
            for (int r = 0; r < 4; ++r) {
                int row = bm * 128 + wm + mt * 16 + q4 * 4 + r;
                size_t idx = (size_t)row * 1024 + col;
                float v = x[idx] + acc[mt][nt][r];
                if (col == 1009) v += gch[row];
                else if (col == 1011) v += pch[row];
                else if (col == 1021) v = pch[row];
                out[idx] = v;
            }
        }
    }
}

// ---------------------------------------------------------------------------
extern "C" void kernel_launch(void* const* d_in, const int* in_sizes, int n_in,
                              void* d_out, int out_size, void* d_ws, size_t ws_size,
                              hipStream_t stream) {
    (void)in_sizes; (void)n_in; (void)out_size; (void)ws_size;
    const float* x   = (const float*)d_in[0];
    const float* gch = (const float*)d_in[1];
    const float* pch = (const float*)d_in[2];
    const float* wq  = (const float*)d_in[3];
    const float* wk  = (const float*)d_in[4];
    const float* wv  = (const float*)d_in[5];
    const float* wo  = (const float*)d_in[6];
    float* out = (float*)d_out;

    char* ws = (char*)d_ws;
    bf16* Xb    = (bf16*)(ws);
    bf16* WqkvT = (bf16*)(ws + (size_t)( 8 << 20));
    bf16* WoT   = (bf16*)(ws + (size_t)(14 << 20));
    bf16* QK    = (bf16*)(ws + (size_t)(16 << 20));
    bf16* Vt    = (bf16*)(ws + (size_t)(32 << 20));
    bf16* AO    = Xb;  // Xb dead after gemm_qkv

    cast_x_kernel<<<4096, 256, 0, stream>>>(x, Xb);
    transpose_cast_kernel<<<1024, 256, 0, stream>>>(wq, wk, wv, wo, WqkvT, WoT);
    gemm_qkv_kernel<<<dim3(32, 24), 256, 0, stream>>>(Xb, WqkvT, QK, Vt);
    attn_kernel<<<1024, 256, 0, stream>>>(QK, Vt, x, gch, AO);
    gemm_out_kernel<<<dim3(32, 8), 256, 0, stream>>>(AO, WoT, x, gch, pch, out);
}

// Round 5
// 212.238 us; speedup vs baseline: 1.0086x; 1.0086x over previous
//
#include <hip/hip_runtime.h>
#include <hip/hip_bf16.h>

typedef __hip_bfloat16 bf16;
typedef __attribute__((ext_vector_type(8))) short short8;   // 8 bf16 = 4 VGPRs (x32 A/B frag)
typedef __attribute__((ext_vector_type(4))) short short4v;  // 4 bf16 = 2 VGPRs (x16 A/B frag)
typedef __attribute__((ext_vector_type(4))) float f32x4;    // MFMA C/D frag

#define MFMA16(a, b, c) __builtin_amdgcn_mfma_f32_16x16x32_bf16((a), (b), (c), 0, 0, 0)

// 16x16x16 bf16 MFMA: builtin name varies across ROCm; asm fallback.
#if __has_builtin(__builtin_amdgcn_mfma_f32_16x16x16bf16_1k)
#define MFMA_PV(a, b, c) __builtin_amdgcn_mfma_f32_16x16x16bf16_1k((a), (b), (c), 0, 0, 0)
#elif __has_builtin(__builtin_amdgcn_mfma_f32_16x16x16_bf16)
#define MFMA_PV(a, b, c) __builtin_amdgcn_mfma_f32_16x16x16_bf16((a), (b), (c), 0, 0, 0)
#else
static __device__ __forceinline__ f32x4 mfma_pv_asm(short4v a, short4v b, f32x4 c) {
    f32x4 d;
    asm volatile("v_mfma_f32_16x16x16_bf16 %0, %1, %2, %3"
                 : "=&v"(d) : "v"(a), "v"(b), "v"(c));
    return d;
}
#define MFMA_PV(a, b, c) mfma_pv_asm((a), (b), (c))
#endif

// async global->LDS, 16B per lane; LDS dest must be wave-uniform base + lane*16
static __device__ __forceinline__ void gload_lds16(const bf16* g, bf16* l) {
    __builtin_amdgcn_global_load_lds((const __attribute__((address_space(1))) void*)g,
                                     (__attribute__((address_space(3))) void*)l, 16, 0, 0);
}

// ---------------------------------------------------------------------------
// Kernel 1: fused prep — cast x -> bf16 (blocks 0..4095) and weight
// transpose+cast (blocks 4096..5119).
// ---------------------------------------------------------------------------
__global__ __launch_bounds__(256) void prep_kernel(
    const float* __restrict__ x,
    const float* __restrict__ wq, const float* __restrict__ wk,
    const float* __restrict__ wv, const float* __restrict__ wo,
    bf16* __restrict__ Xb, bf16* __restrict__ WqkvT, bf16* __restrict__ WoT) {
    __shared__ bf16 tile[64][65];
    int bid = blockIdx.x;
    if (bid < 4096) {
        int i = (bid * 256 + threadIdx.x) * 4;
        float4 v = *(const float4*)(x + i);
        union { bf16 h4[4]; uint2 u; } p;
        p.h4[0] = __float2bfloat16(v.x);
        p.h4[1] = __float2bfloat16(v.y);
        p.h4[2] = __float2bfloat16(v.z);
        p.h4[3] = __float2bfloat16(v.w);
        *(uint2*)(Xb + i) = p.u;
        return;
    }
    int t2 = bid - 4096;
    int mat = t2 >> 8;
    int t   = t2 & 255;
    int tn  = t >> 4, tk = t & 15;
    const float* src = (mat == 0) ? wq : (mat == 1) ? wk : (mat == 2) ? wv : wo;
    bf16* dst = (mat < 3) ? (WqkvT + (size_t)mat * 1024 * 1024) : WoT;
    int tx = threadIdx.x & 63, ty = threadIdx.x >> 6;
    int k0 = tk * 64, n0 = tn * 64;
#pragma unroll
    for (int p = 0; p < 16; ++p) {
        int r = p * 4 + ty;
        tile[r][tx] = __float2bfloat16(src[(size_t)(k0 + r) * 1024 + n0 + tx]);
    }
    __syncthreads();
#pragma unroll
    for (int p = 0; p < 16; ++p) {
        int r = p * 4 + ty;
        dst[(size_t)(n0 + r) * 1024 + k0 + tx] = tile[tx][r];
    }
}

// ---------------------------------------------------------------------------
// Kernel 2: GEMM1  QKV = Xb @ WqkvT^T, global_load_lds staging.
// Q columns (bn<8) are PRESCALED by 0.125*log2(e) for the attn softmax.
// ---------------------------------------------------------------------------
__global__ __launch_bounds__(256) void gemm_qkv_kernel(
    const bf16* __restrict__ A, const bf16* __restrict__ Bt,
    bf16* __restrict__ QK, bf16* __restrict__ Vt) {
    const int K = 1024;
    int bm = blockIdx.x, bn = blockIdx.y;
    __shared__ bf16 As[128 * 32];
    __shared__ bf16 Bs[128 * 32];
    int tid = threadIdx.x;
    int lane = tid & 63, w = tid >> 6;
    int wm = (w >> 1) * 64, wn = (w & 1) * 64;
    int q4 = lane >> 4, li = lane & 15;
    int srow = tid >> 2, sc = (tid & 3) * 8;

    const bf16* Ag = A + (size_t)(bm * 128 + srow) * K + sc;
    const bf16* Bg = Bt + (size_t)(bn * 128 + srow) * K + sc;
    bf16* Asl = As + tid * 8;
    bf16* Asl2 = As + 2048 + tid * 8;
    bf16* Bsl = Bs + tid * 8;
    bf16* Bsl2 = Bs + 2048 + tid * 8;

    f32x4 acc[4][4];
#pragma unroll
    for (int mt = 0; mt < 4; ++mt)
#pragma unroll
        for (int nt = 0; nt < 4; ++nt) acc[mt][nt] = (f32x4){0.f, 0.f, 0.f, 0.f};

    for (int k0 = 0; k0 < K; k0 += 32) {
        __syncthreads();
        gload_lds16(Ag + k0, Asl);
        gload_lds16(Ag + 64 * K + k0, Asl2);
        gload_lds16(Bg + k0, Bsl);
        gload_lds16(Bg + 64 * K + k0, Bsl2);
        __syncthreads();
        short8 af[4], bfb[4];
#pragma unroll
        for (int mt = 0; mt < 4; ++mt)
            af[mt] = *(const short8*)(As + (wm + mt * 16 + li) * 32 + q4 * 8);
#pragma unroll
        for (int nt = 0; nt < 4; ++nt)
            bfb[nt] = *(const short8*)(Bs + (wn + nt * 16 + li) * 32 + q4 * 8);
#pragma unroll
        for (int mt = 0; mt < 4; ++mt)
#pragma unroll
            for (int nt = 0; nt < 4; ++nt)
                acc[mt][nt] = MFMA16(af[mt], bfb[nt], acc[mt][nt]);
    }

    int rowb = bm * 128 + wm;
    if (bn < 16) {
        float qs = (bn < 8) ? 0.1803368801111244f : 1.0f;   // 0.125*log2(e) on Q
#pragma unroll
        for (int mt = 0; mt < 4; ++mt) {
#pragma unroll
            for (int nt = 0; nt < 4; ++nt) {
                int col = bn * 128 + wn + nt * 16 + li;
#pragma unroll
                for (int r = 0; r < 4; ++r) {
                    int row = rowb + mt * 16 + q4 * 4 + r;
                    QK[(size_t)row * 2048 + col] = __float2bfloat16(acc[mt][nt][r] * qs);
                }
            }
        }
    } else {
#pragma unroll
        for (int mt = 0; mt < 4; ++mt) {
            int sbase = rowb + mt * 16 + q4 * 4;
            int b = sbase >> 11, s = sbase & 2047;
#pragma unroll
            for (int nt = 0; nt < 4; ++nt) {
                int n = bn * 128 + wn + nt * 16 + li - 2048;
                int h = n >> 6, d = n & 63;
                union { bf16 h4[4]; uint2 u; } pk;
#pragma unroll
                for (int r = 0; r < 4; ++r) pk.h4[r] = __float2bfloat16(acc[mt][nt][r]);
                *(uint2*)(Vt + (size_t)((b * 16 + h) * 64 + d) * 2048 + s) = pk.u;
            }
        }
    }
}

// ---------------------------------------------------------------------------
// Kernel 3: flash attention — j-split waves (1x LDS amplification) +
// double-buffered single-barrier pipeline.
//  - wave w owns j-slice [w*16, w*16+16) of each 64-key tile, ALL 64 q rows.
//  - S^T = K·Q^T; its C-frags ARE P^T A-frags for O = P^T-as-A · V^T-as-B:
//    no P LDS round trip.
//  - end-of-block cross-wave O reduction through LDS ALIASED over the dead
//    K/V double buffers (LDS stays 36864 B).
//  - Q prescaled by 0.125*log2e in gemm_qkv; softmax in exp2 domain, no max.
// ---------------------------------------------------------------------------
__global__ __launch_bounds__(256, 3) void attn_kernel(
    const bf16* __restrict__ QK, const bf16* __restrict__ Vt,
    const float* __restrict__ x, const float* __restrict__ gch,
    bf16* __restrict__ AO) {
    const int S = 2048;
    // LPT schedule: h=0 blocks (32 tiles) first, then causal descending ti.
    int idx = blockIdx.x;
    int ti, h, b;
    if (idx < 64) { h = 0; b = idx & 1; ti = idx >> 1; }
    else {
        int i2 = idx - 64;
        int row = i2 / 30;
        int j = i2 - row * 30;
        ti = 31 - row; h = 1 + (j >> 1); b = j & 1;
    }
    int i0 = ti * 64;
    int tid = threadIdx.x, lane = tid & 63, w = tid >> 6;
    int q4 = lane >> 4, li = lane & 15;

    __shared__ __align__(16) char smem[36864];
    bf16* Ks0 = (bf16*)(smem);              // K tile [j][d], pitch 72
    bf16* Ks1 = (bf16*)(smem + 9216);
    bf16* Vs0 = (bf16*)(smem + 18432);      // V^T tile [d][j], pitch 72
    bf16* Vs1 = (bf16*)(smem + 27648);
    float* Ored  = (float*)(smem);          // [64][68] fp32, alias (post-loop)
    float* lsumB = (float*)(smem + 17408);  // [4][64] fp32, alias (post-loop)

    // Q frags (B-operand of S^T) for all 4 q-subtiles
    short8 qf[4][2];
#pragma unroll
    for (int it = 0; it < 4; ++it) {
        const bf16* qp = QK + (size_t)(b * S + i0 + it * 16 + li) * 2048 + h * 64 + q4 * 8;
        qf[it][0] = *(const short8*)(qp);
        qf[it][1] = *(const short8*)(qp + 32);
    }

    const float L2E = 1.4426950408889634f;
    float sl1 = exp2f(-0.5f * (float)(h + 1)) * L2E;   // coeff of (j - i)
    const float slope0L = 0.70710678118654752f * L2E;

    float tgt[4]; int gcm[4];
    if (h == 0) {
#pragma unroll
        for (int it = 0; it < 4; ++it) {
            size_t ix = (size_t)(b * S + i0 + it * 16 + li);
            gcm[it] = gch[ix] > 0.5f ? 1 : 0;
            tgt[it] = x[ix * 1024 + 1008] + 1.0f + x[ix * 1024 + 1009];
        }
    } else {
#pragma unroll
        for (int it = 0; it < 4; ++it) { gcm[it] = 0; tgt[it] = 0.f; }
    }

    float lsum[4] = {0.f, 0.f, 0.f, 0.f};
    f32x4 o[4][4];                     // [it][dt]; D-frag (i=q4*4+r, d=li)
#pragma unroll
    for (int it = 0; it < 4; ++it)
#pragma unroll
        for (int dt = 0; dt < 4; ++dt) o[it][dt] = (f32x4){0.f, 0.f, 0.f, 0.f};

    int srow = tid >> 3, scv = (tid & 7) * 8;
    const bf16* Kg = QK + (size_t)(b * S + srow) * 2048 + 1024 + h * 64 + scv;
    const bf16* Vg = Vt + (size_t)((b * 16 + h) * 64 + srow) * 2048 + scv;

    int ntiles = (h == 0) ? (S / 64) : (ti + 1);

    // prologue: stage tile 0 into buf0, prefetch tile 1 into regs
    uint4 kv0 = *(const uint4*)(Kg);
    uint4 kv1 = *(const uint4*)(Kg + (size_t)32 * 2048);
    uint4 vv0 = *(const uint4*)(Vg);
    uint4 vv1 = *(const uint4*)(Vg + (size_t)32 * 2048);
    *(uint4*)(Ks0 + srow * 72 + scv) = kv0;
    *(uint4*)(Ks0 + (srow + 32) * 72 + scv) = kv1;
    *(uint4*)(Vs0 + srow * 72 + scv) = vv0;
    *(uint4*)(Vs0 + (srow + 32) * 72 + scv) = vv1;
    if (ntiles > 1) {
        kv0 = *(const uint4*)(Kg + (size_t)64 * 2048);
        kv1 = *(const uint4*)(Kg + (size_t)96 * 2048);
        vv0 = *(const uint4*)(Vg + 64);
        vv1 = *(const uint4*)(Vg + (size_t)32 * 2048 + 64);
    }
    __syncthreads();

    for (int jt = 0; jt < ntiles; ++jt) {
        const bf16* Kc = (jt & 1) ? Ks1 : Ks0;
        const bf16* Vc = (jt & 1) ? Vs1 : Vs0;
        if (jt + 1 < ntiles) {
            bf16* Kn = (jt & 1) ? Ks0 : Ks1;
            bf16* Vn = (jt & 1) ? Vs0 : Vs1;
            *(uint4*)(Kn + srow * 72 + scv) = kv0;
            *(uint4*)(Kn + (srow + 32) * 72 + scv) = kv1;
            *(uint4*)(Vn + srow * 72 + scv) = vv0;
            *(uint4*)(Vn + (srow + 32) * 72 + scv) = vv1;
            if (jt + 2 < ntiles) {
                size_t jn = (size_t)(jt + 2) * 64;
                kv0 = *(const uint4*)(Kg + jn * 2048);
                kv1 = *(const uint4*)(Kg + (jn + 32) * 2048);
                vv0 = *(const uint4*)(Vg + jn);
                vv1 = *(const uint4*)(Vg + (size_t)32 * 2048 + jn);
            }
        }

        int j0 = jt * 64;
        // S^T for wave's j-slice: rows j = w*16 + q4*4 + r, cols i per it
        short8 kf0 = *(const short8*)(Kc + (w * 16 + li) * 72 + q4 * 8);
        short8 kf1 = *(const short8*)(Kc + (w * 16 + li) * 72 + 32 + q4 * 8);
        f32x4 sA[4];
#pragma unroll
        for (int it = 0; it < 4; ++it) {
            f32x4 z = (f32x4){0.f, 0.f, 0.f, 0.f};
            z = MFMA16(kf0, qf[it][0], z);
            z = MFMA16(kf1, qf[it][1], z);
            sA[it] = z;
        }

        float jbase = (float)(j0 + w * 16 + q4 * 4);
        bool diag = (jt >= ti);
        short4v pf[4];
#pragma unroll
        for (int it = 0; it < 4; ++it) {
            float fi = (float)(i0 + it * 16 + li);
            float d0 = jbase - fi;
            union { bf16 hh[4]; short4v v; } pu;
#pragma unroll
            for (int r = 0; r < 4; ++r) {
                float dj = d0 + (float)r;
                float p;
                if (h == 0) {
                    float s = fmaf(sl1, dj, sA[it][r]);
                    float sg = -slope0L * fabsf(tgt[it] - (jbase + (float)r));
                    s = gcm[it] ? sg : s;
                    p = exp2f(s);
                    if (!gcm[it] && dj > 0.f) p = 0.f;
                } else {
                    float s = fmaf(sl1, dj, sA[it][r]);
                    p = exp2f(s);
                    if (diag && dj > 0.f) p = 0.f;
                }
                lsum[it] += p;
                pu.hh[r] = __float2bfloat16(p);
            }
            pf[it] = pu.v;
        }

        // O += P^T-as-A · V^T-as-B : D[m=i][n=d], per (it, dt)
#pragma unroll
        for (int dt = 0; dt < 4; ++dt) {
            short4v vf = *(const short4v*)(Vc + (dt * 16 + li) * 72 + w * 16 + q4 * 4);
#pragma unroll
            for (int it = 0; it < 4; ++it)
                o[it][dt] = MFMA_PV(pf[it], vf, o[it][dt]);
        }
        __syncthreads();
    }
    // (loop ends with a barrier: all waves done reading K/V -> aliasing safe)

    // lsum: combine the 4 q4 groups (same i = li, different j)
#pragma unroll
    for (int it = 0; it < 4; ++it) {
        lsum[it] += __shfl_xor(lsum[it], 16, 64);
        lsum[it] += __shfl_xor(lsum[it], 32, 64);
    }
    if (lane < 16) {
#pragma unroll
        for (int it = 0; it < 4; ++it) lsumB[w * 64 + it * 16 + lane] = lsum[it];
    }

    // cross-wave O reduction (serial RMW rounds into aliased Ored)
    __syncthreads();
    if (w == 0) {
#pragma unroll
        for (int it = 0; it < 4; ++it)
#pragma unroll
            for (int dt = 0; dt < 4; ++dt)
#pragma unroll
                for (int r = 0; r < 4; ++r)
                    Ored[(it * 16 + q4 * 4 + r) * 68 + dt * 16 + li] = o[it][dt][r];
    }
    __syncthreads();
    if (w == 1) {
#pragma unroll
        for (int it = 0; it < 4; ++it)
#pragma unroll
            for (int dt = 0; dt < 4; ++dt)
#pragma unroll
                for (int r = 0; r < 4; ++r)
                    Ored[(it * 16 + q4 * 4 + r) * 68 + dt * 16 + li] += o[it][dt][r];
    }
    __syncthreads();
    if (w == 2) {
#pragma unroll
        for (int it = 0; it < 4; ++it)
#pragma unroll
            for (int dt = 0; dt < 4; ++dt)
#pragma unroll
                for (int r = 0; r < 4; ++r)
                    Ored[(it * 16 + q4 * 4 + r) * 68 + dt * 16 + li] += o[it][dt][r];
    }
    __syncthreads();
    if (w == 3) {
#pragma unroll
        for (int it = 0; it < 4; ++it)
#pragma unroll
            for (int dt = 0; dt < 4; ++dt)
#pragma unroll
                for (int r = 0; r < 4; ++r)
                    Ored[(it * 16 + q4 * 4 + r) * 68 + dt * 16 + li] += o[it][dt][r];
    }
    __syncthreads();

    // epilogue: thread t -> row i = t>>2, 16-wide d segment
    int i = tid >> 2, dseg = (tid & 3) * 16;
    float ls = lsumB[i] + lsumB[64 + i] + lsumB[128 + i] + lsumB[192 + i];
    float inv = 1.0f / ls;
    bf16* dst = AO + (size_t)(b * S + i0 + i) * 1024 + h * 64 + dseg;
    union { bf16 hh[16]; uint4 u[2]; } ou;
#pragma unroll
    for (int c = 0; c < 16; ++c)
        ou.hh[c] = __float2bfloat16(Ored[i * 68 + dseg + c] * inv);
    *(uint4*)(dst) = ou.u[0];
    *(uint4*)(dst + 8) = ou.u[1];
}

// ---------------------------------------------------------------------------
// Kernel 4: GEMM2  out = x + AO @ WoT^T (fp32 out) + fused I/O fixups
// ---------------------------------------------------------------------------
__global__ __launch_bounds__(256) void gemm_out_kernel(
    const bf16* __restrict__ A, const bf16* __restrict__ Bt,
    const float* __restrict__ x, const float* __restrict__ gch,
    const float* __restrict__ pch, float* __restrict__ out) {
    const int K = 1024;
    int bm = blockIdx.x, bn = blockIdx.y;
    __shared__ bf16 As[128 * 32];
    __shared__ bf16 Bs[128 * 32];
    int tid = threadIdx.x;
    int lane = tid & 63, w = tid >> 6;
    int wm = (w >> 1) * 64, wn = (w & 1) * 64;
    int q4 = lane >> 4, li = lane & 15;
    int srow = tid >> 2, sc = (tid & 3) * 8;

    const bf16* Ag = A + (size_t)(bm * 128 + srow) * K + sc;
    const bf16* Bg = Bt + (size_t)(bn * 128 + srow) * K + sc;
    bf16* Asl = As + tid * 8;
    bf16* Asl2 = As + 2048 + tid * 8;
    bf16* Bsl = Bs + tid * 8;
    bf16* Bsl2 = Bs + 2048 + tid * 8;

    f32x4 acc[4][4];
#pragma unroll
    for (int mt = 0; mt < 4; ++mt)
#pragma unroll
        for (int nt = 0; nt < 4; ++nt) acc[mt][nt] = (f32x4){0.f, 0.f, 0.f, 0.f};

    for (int k0 = 0; k0 < K; k0 += 32) {
        __syncthreads();
        gload_lds16(Ag + k0, Asl);
        gload_lds16(Ag + 64 * K + k0, Asl2);
        gload_lds16(Bg + k0, Bsl);
        gload_lds16(Bg + 64 * K + k0, Bsl2);
        __syncthreads();
        short8 af[4], bfb[4];
#pragma unroll
        for (int mt = 0; mt < 4; ++mt)
            af[mt] = *(const short8*)(As + (wm + mt * 16 + li) * 32 + q4 * 8);
#pragma unroll
        for (int nt = 0; nt < 4; ++nt)
            bfb[nt] = *(const short8*)(Bs + (wn + nt * 16 + li) * 32 + q4 * 8);
#pragma unroll
        for (int mt = 0; mt < 4; ++mt)
#pragma unroll
            for (int nt = 0; nt < 4; ++nt)
                acc[mt][nt] = MFMA16(af[mt], bfb[nt], acc[mt][nt]);
    }

#pragma unroll
    for (int mt = 0; mt < 4; ++mt) {
#pragma unroll
        for (int nt = 0; nt < 4; ++nt) {
            int col = bn * 128 + wn + nt * 16 + li;
#pragma unroll
            for (int r = 0; r < 4; ++r) {
                int row = bm * 128 + wm + mt * 16 + q4 * 4 + r;
                size_t idx = (size_t)row * 1024 + col;
                float v = x[idx] + acc[mt][nt][r];
                if (col == 1009) v += gch[row];
                else if (col == 1011) v += pch[row];
                else if (col == 1021) v = pch[row];
                out[idx] = v;
            }
        }
    }
}

// ---------------------------------------------------------------------------
extern "C" void kernel_launch(void* const* d_in, const int* in_sizes, int n_in,
                              void* d_out, int out_size, void* d_ws, size_t ws_size,
                              hipStream_t stream) {
    (void)in_sizes; (void)n_in; (void)out_size; (void)ws_size;
    const float* x   = (const float*)d_in[0];
    const float* gch = (const float*)d_in[1];
    const float* pch = (const float*)d_in[2];
    const float* wq  = (const float*)d_in[3];
    const float* wk  = (const float*)d_in[4];
    const float* wv  = (const float*)d_in[5];
    const float* wo  = (const float*)d_in[6];
    float* out = (float*)d_out;

    char* ws = (char*)d_ws;
    bf16* Xb    = (bf16*)(ws);
    bf16* WqkvT = (bf16*)(ws + (size_t)( 8 << 20));
    bf16* WoT   = (bf16*)(ws + (size_t)(14 << 20));
    bf16* QK    = (bf16*)(ws + (size_t)(16 << 20));
    bf16* Vt    = (bf16*)(ws + (size_t)(32 << 20));
    bf16* AO    = Xb;  // Xb dead after gemm_qkv

    prep_kernel<<<5120, 256, 0, stream>>>(x, wq, wk, wv, wo, Xb, WqkvT, WoT);
    gemm_qkv_kernel<<<dim3(32, 24), 256, 0, stream>>>(Xb, WqkvT, QK, Vt);
    attn_kernel<<<1024, 256, 0, stream>>>(QK, Vt, x, gch, AO);
    gemm_out_kernel<<<dim3(32, 8), 256, 0, stream>>>(AO, WoT, x, gch, pch, out);
}